// Round 2
// baseline (527.383 us; speedup 1.0000x reference)
//
#include <hip/hip_runtime.h>

// y[b,h,l] = sum_{m<=l} x[b,h,m] k[h,l-m] + D[h] x[b,h,l]   (C = 1)
// Per-h block: K = FFT(k) once; then for batch pairs (0,1),(2,3):
//   z = x_b0 + i x_b1 ; Y = FFT(z)*K/N ; ifft(Y) = y_b0 + i y_b1 (both real).
#define Bdim 4
#define Hdim 1024
#define Ldim 4096
#define NFFT 8192            // 2*L zero-padded FFT length
#define NTHR 256
#define BPT  (NFFT / 2 / NTHR)   // butterflies per thread per stage = 16
#define EPT  (Ldim / NTHR)       // length-4096 elements per thread = 16
#define SPT  (NFFT / NTHR)       // spectrum elements per thread = 32

// v_sin_f32 / v_cos_f32 take input in REVOLUTIONS (D = sin(S0*2pi)).
__device__ __forceinline__ void sincos_rev(float f, float& s, float& c) {
#if __has_builtin(__builtin_amdgcn_sinf) && __has_builtin(__builtin_amdgcn_cosf)
    s = __builtin_amdgcn_sinf(f);
    c = __builtin_amdgcn_cosf(f);
#else
    __sincosf(f * 6.28318530717958647692f, &s, &c);
#endif
}

__device__ __forceinline__ float2 cmul(float2 a, float2 b) {
    return make_float2(a.x * b.x - a.y * b.y, a.x * b.y + a.y * b.x);
}

// Forward radix-2 DIF stages m = NFFT/2 .. 2 (stage m=NFFT fused at load).
// Natural -> bit-reversed. Twiddle W_m^j = exp(-2pi*i*j/m), j=(tid+256r)&(half-1).
// half>=256: W_m^j = W_m^tid * (W_m^256)^(r mod half/256)  -> recurrence.
// half< 256: j = tid&(half-1), constant across r          -> 1 sincos/stage.
__device__ __forceinline__ void dif_stages(float2* A, int tid) {
    for (int m = NFFT >> 1; m >= 2; m >>= 1) {
        const int half = m >> 1;
        const float invm = 1.0f / (float)m;   // power of two: exact
        float2 w0, wstep;
        if (half >= NTHR) {
            sincos_rev(-(float)tid * invm, w0.y, w0.x);
            sincos_rev(-(float)NTHR * invm, wstep.y, wstep.x);
        } else {
            sincos_rev(-(float)(tid & (half - 1)) * invm, w0.y, w0.x);
        }
        float2 w = w0;
        const int H = half >> 8;              // half/NTHR (>=1 when half>=NTHR)
        #pragma unroll
        for (int r = 0; r < BPT; ++r) {
            int t  = tid + r * NTHR;
            int i1 = ((t & ~(half - 1)) << 1) | (t & (half - 1));
            int i2 = i1 + half;
            float2 u = A[i1];
            float2 v = A[i2];
            A[i1] = make_float2(u.x + v.x, u.y + v.y);
            float2 d = make_float2(u.x - v.x, u.y - v.y);
            A[i2] = cmul(d, w);
            if (half >= NTHR) {               // advance/reset twiddle
                if (((r + 1) & (H - 1)) == 0) w = w0;
                else                          w = cmul(w, wstep);
            }
        }
        __syncthreads();
    }
}

// Inverse radix-2 DIT stages m = 2 .. NFFT. Bit-reversed -> natural.
// Twiddle W_m^{-j} -> exp(+2pi*i*j/m). Unnormalized (1/N folded in pointwise).
__device__ __forceinline__ void dit_stages(float2* A, int tid) {
    for (int m = 2; m <= NFFT; m <<= 1) {
        const int half = m >> 1;
        const float invm = 1.0f / (float)m;
        float2 w0, wstep;
        if (half >= NTHR) {
            sincos_rev((float)tid * invm, w0.y, w0.x);
            sincos_rev((float)NTHR * invm, wstep.y, wstep.x);
        } else {
            sincos_rev((float)(tid & (half - 1)) * invm, w0.y, w0.x);
        }
        float2 w = w0;
        const int H = half >> 8;
        #pragma unroll
        for (int r = 0; r < BPT; ++r) {
            int t  = tid + r * NTHR;
            int i1 = ((t & ~(half - 1)) << 1) | (t & (half - 1));
            int i2 = i1 + half;
            float2 v = cmul(A[i2], w);
            float2 u = A[i1];
            A[i1] = make_float2(u.x + v.x, u.y + v.y);
            A[i2] = make_float2(u.x - v.x, u.y - v.y);
            if (half >= NTHR) {
                if (((r + 1) & (H - 1)) == 0) w = w0;
                else                          w = cmul(w, wstep);
            }
        }
        __syncthreads();
    }
}

__global__ __launch_bounds__(NTHR)
void fftconv_kernel(const float* __restrict__ x,
                    const float* __restrict__ kin,
                    const float* __restrict__ Din,
                    float* __restrict__ out)
{
    __shared__ float2 A[NFFT];   // 64 KiB -> 2 blocks/CU

    const int tid = threadIdx.x;
    const int h = blockIdx.x;               // one block per h, all 4 batches

    const float* kp = kin + (size_t)h * (size_t)Ldim;   // C = 1
    const float  Dh = Din[h];
    const float  invN = 1.0f / (float)NFFT;

    // ---- K: load + fused DIF stage m=NFFT (upper half zero) ----
    // A[j] = v ; A[j+4096] = v * W_NFFT^{-j}, with W recurrence over r.
    {
        float2 w, wstep;
        sincos_rev(-(float)tid * (1.0f / (float)NFFT), w.y, w.x);
        sincos_rev(-(float)NTHR * (1.0f / (float)NFFT), wstep.y, wstep.x);
        #pragma unroll
        for (int r = 0; r < EPT; ++r) {
            int j = tid + r * NTHR;
            float v = kp[j];
            A[j]        = make_float2(v, 0.0f);
            A[j + Ldim] = make_float2(v * w.x, v * w.y);
            w = cmul(w, wstep);
        }
    }
    __syncthreads();
    dif_stages(A, tid);                        // ends with barrier

    // Stash K spectrum (bitrev order), own slots only -> no barrier needed.
    float2 kspec[SPT];
    #pragma unroll
    for (int r = 0; r < SPT; ++r) kspec[r] = A[tid + r * NTHR];

    for (int p = 0; p < 2; ++p) {
        const float* xp0 = x + ((size_t)(2 * p)     * Hdim + h) * (size_t)Ldim;
        const float* xp1 = x + ((size_t)(2 * p + 1) * Hdim + h) * (size_t)Ldim;

        // ---- z = x_b0 + i x_b1: load + fused first DIF stage ----
        float xr0[EPT], xr1[EPT];              // keep for the skip term
        {
            float2 w, wstep;
            sincos_rev(-(float)tid * (1.0f / (float)NFFT), w.y, w.x);
            sincos_rev(-(float)NTHR * (1.0f / (float)NFFT), wstep.y, wstep.x);
            #pragma unroll
            for (int r = 0; r < EPT; ++r) {
                int j = tid + r * NTHR;
                float2 z = make_float2(xp0[j], xp1[j]);
                xr0[r] = z.x; xr1[r] = z.y;
                A[j]        = z;               // own slots only
                A[j + Ldim] = cmul(z, w);
                w = cmul(w, wstep);
            }
        }
        __syncthreads();
        dif_stages(A, tid);                    // ends with barrier

        // ---- pointwise Y = Z * K / N (both spectra share bitrev order) ----
        #pragma unroll
        for (int r = 0; r < SPT; ++r) {
            int q = tid + r * NTHR;            // own slots
            float2 v = cmul(A[q], kspec[r]);
            A[q] = make_float2(v.x * invN, v.y * invN);
        }
        __syncthreads();
        dit_stages(A, tid);                    // ends with barrier

        // ---- epilogue: y_b0 = Re + D*x0 ; y_b1 = Im + D*x1 (own slots) ----
        float* op0 = out + ((size_t)(2 * p)     * Hdim + h) * (size_t)Ldim;
        float* op1 = out + ((size_t)(2 * p + 1) * Hdim + h) * (size_t)Ldim;
        #pragma unroll
        for (int r = 0; r < EPT; ++r) {
            int j = tid + r * NTHR;
            float2 yv = A[j];
            op0[j] = yv.x + Dh * xr0[r];
            op1[j] = yv.y + Dh * xr1[r];
        }
        // next pair's z-store writes own slots only -> no barrier needed
    }
}

extern "C" void kernel_launch(void* const* d_in, const int* in_sizes, int n_in,
                              void* d_out, int out_size, void* d_ws, size_t ws_size,
                              hipStream_t stream)
{
    const float* x  = (const float*)d_in[0];
    const float* k  = (const float*)d_in[1];
    const float* D  = (const float*)d_in[2];
    float* out = (float*)d_out;

    dim3 grid(Hdim);          // one block per h
    dim3 block(NTHR);
    hipLaunchKernelGGL(fftconv_kernel, grid, block, 0, stream, x, k, D, out);
}

// Round 3
// 477.766 us; speedup vs baseline: 1.1039x; 1.1039x over previous
//
#include <hip/hip_runtime.h>

// y[b,h,l] = sum_{m<=l} x[b,h,m] k[h,l-m] + D[h] x[b,h,l]   (C = 1)
// Per-h block: K = FFT(k) once; then for batch pairs (0,1),(2,3):
//   z = x_b0 + i x_b1 ; Y = FFT(z)*K/N ; ifft(Y) = y_b0 + i y_b1 (both real).
#define Bdim 4
#define Hdim 1024
#define Ldim 4096
#define NFFT 8192            // 2*L zero-padded FFT length
#define NTHR 512
#define LOG2T 9
#define BPT  (NFFT / 2 / NTHR)   // butterflies per thread per stage = 8
#define EPT  (Ldim / NTHR)       // length-4096 elements per thread = 8
#define SPT  (NFFT / NTHR)       // spectrum elements per thread = 16

// v_sin_f32 / v_cos_f32 take input in REVOLUTIONS (D = sin(S0*2pi)).
__device__ __forceinline__ void sincos_rev(float f, float& s, float& c) {
#if __has_builtin(__builtin_amdgcn_sinf) && __has_builtin(__builtin_amdgcn_cosf)
    s = __builtin_amdgcn_sinf(f);
    c = __builtin_amdgcn_cosf(f);
#else
    __sincosf(f * 6.28318530717958647692f, &s, &c);
#endif
}

__device__ __forceinline__ float2 cmul(float2 a, float2 b) {
    return make_float2(a.x * b.x - a.y * b.y, a.x * b.y + a.y * b.x);
}

// Forward radix-2 DIF stages m = NFFT/2 .. 2 (stage m=NFFT fused at load).
// Natural -> bit-reversed. Twiddle W_m^j = exp(-2pi*i*j/m), j=(tid+NTHR*r)&(half-1).
// half>=NTHR: W_m^j = W_m^tid * (W_m^NTHR)^(r mod half/NTHR)  -> recurrence.
// half< NTHR: j = tid&(half-1), constant across r             -> 1 sincos/stage.
__device__ __forceinline__ void dif_stages(float2* A, int tid) {
    for (int m = NFFT >> 1; m >= 2; m >>= 1) {
        const int half = m >> 1;
        const float invm = 1.0f / (float)m;   // power of two: exact
        float2 w0, wstep = make_float2(1.0f, 0.0f);
        if (half >= NTHR) {
            sincos_rev(-(float)tid * invm, w0.y, w0.x);
            sincos_rev(-(float)NTHR * invm, wstep.y, wstep.x);
        } else {
            sincos_rev(-(float)(tid & (half - 1)) * invm, w0.y, w0.x);
        }
        float2 w = w0;
        const int H = half >> LOG2T;          // half/NTHR (>=1 when half>=NTHR)
        #pragma unroll
        for (int r = 0; r < BPT; ++r) {
            int t  = tid + r * NTHR;
            int i1 = ((t & ~(half - 1)) << 1) | (t & (half - 1));
            int i2 = i1 + half;
            float2 u = A[i1];
            float2 v = A[i2];
            A[i1] = make_float2(u.x + v.x, u.y + v.y);
            float2 d = make_float2(u.x - v.x, u.y - v.y);
            A[i2] = cmul(d, w);
            if (half >= NTHR) {               // advance/reset twiddle
                if (((r + 1) & (H - 1)) == 0) w = w0;
                else                          w = cmul(w, wstep);
            }
        }
        __syncthreads();
    }
}

// Inverse radix-2 DIT stages m = 2 .. NFFT. Bit-reversed -> natural.
// Twiddle exp(+2pi*i*j/m). Unnormalized (1/N folded in pointwise).
__device__ __forceinline__ void dit_stages(float2* A, int tid) {
    for (int m = 2; m <= NFFT; m <<= 1) {
        const int half = m >> 1;
        const float invm = 1.0f / (float)m;
        float2 w0, wstep = make_float2(1.0f, 0.0f);
        if (half >= NTHR) {
            sincos_rev((float)tid * invm, w0.y, w0.x);
            sincos_rev((float)NTHR * invm, wstep.y, wstep.x);
        } else {
            sincos_rev((float)(tid & (half - 1)) * invm, w0.y, w0.x);
        }
        float2 w = w0;
        const int H = half >> LOG2T;
        #pragma unroll
        for (int r = 0; r < BPT; ++r) {
            int t  = tid + r * NTHR;
            int i1 = ((t & ~(half - 1)) << 1) | (t & (half - 1));
            int i2 = i1 + half;
            float2 v = cmul(A[i2], w);
            float2 u = A[i1];
            A[i1] = make_float2(u.x + v.x, u.y + v.y);
            A[i2] = make_float2(u.x - v.x, u.y - v.y);
            if (half >= NTHR) {
                if (((r + 1) & (H - 1)) == 0) w = w0;
                else                          w = cmul(w, wstep);
            }
        }
        __syncthreads();
    }
}

__global__ __launch_bounds__(NTHR, 4)
void fftconv_kernel(const float* __restrict__ x,
                    const float* __restrict__ kin,
                    const float* __restrict__ Din,
                    float* __restrict__ out)
{
    __shared__ float2 A[NFFT];   // 64 KiB -> 2 blocks/CU

    const int tid = threadIdx.x;
    const int h = blockIdx.x;               // one block per h, all 4 batches

    const float* kp = kin + (size_t)h * (size_t)Ldim;   // C = 1
    const float  Dh = Din[h];
    const float  invN = 1.0f / (float)NFFT;

    // First-stage twiddles (m = NFFT): W^tid and step W^NTHR, reused for K and z.
    float2 wf0, wfstep;
    sincos_rev(-(float)tid * (1.0f / (float)NFFT), wf0.y, wf0.x);
    sincos_rev(-(float)NTHR * (1.0f / (float)NFFT), wfstep.y, wfstep.x);

    // ---- K: load + fused DIF stage m=NFFT (upper half of input is zero) ----
    {
        float2 w = wf0;
        #pragma unroll
        for (int r = 0; r < EPT; ++r) {
            int j = tid + r * NTHR;
            float v = kp[j];
            A[j]        = make_float2(v, 0.0f);
            A[j + Ldim] = make_float2(v * w.x, v * w.y);
            w = cmul(w, wfstep);
        }
    }
    __syncthreads();
    dif_stages(A, tid);                        // ends with barrier

    // Stash K spectrum (bitrev order), own slots only -> no barrier needed.
    float2 kspec[SPT];
    #pragma unroll
    for (int r = 0; r < SPT; ++r) kspec[r] = A[tid + r * NTHR];

    for (int p = 0; p < 2; ++p) {
        const float* xp0 = x + ((size_t)(2 * p)     * Hdim + h) * (size_t)Ldim;
        const float* xp1 = x + ((size_t)(2 * p + 1) * Hdim + h) * (size_t)Ldim;

        // ---- z = x_b0 + i x_b1: load + fused first DIF stage ----
        float xr0[EPT], xr1[EPT];              // keep for the skip term
        {
            float2 w = wf0;
            #pragma unroll
            for (int r = 0; r < EPT; ++r) {
                int j = tid + r * NTHR;
                float2 z = make_float2(xp0[j], xp1[j]);
                xr0[r] = z.x; xr1[r] = z.y;
                A[j]        = z;               // own slots only
                A[j + Ldim] = cmul(z, w);
                w = cmul(w, wfstep);
            }
        }
        __syncthreads();
        dif_stages(A, tid);                    // ends with barrier

        // ---- pointwise Y = Z * K / N (both spectra share bitrev order) ----
        #pragma unroll
        for (int r = 0; r < SPT; ++r) {
            int q = tid + r * NTHR;            // own slots
            float2 v = cmul(A[q], kspec[r]);
            A[q] = make_float2(v.x * invN, v.y * invN);
        }
        __syncthreads();
        dit_stages(A, tid);                    // ends with barrier

        // ---- epilogue: y_b0 = Re + D*x0 ; y_b1 = Im + D*x1 (own slots) ----
        float* op0 = out + ((size_t)(2 * p)     * Hdim + h) * (size_t)Ldim;
        float* op1 = out + ((size_t)(2 * p + 1) * Hdim + h) * (size_t)Ldim;
        #pragma unroll
        for (int r = 0; r < EPT; ++r) {
            int j = tid + r * NTHR;
            float2 yv = A[j];
            op0[j] = yv.x + Dh * xr0[r];
            op1[j] = yv.y + Dh * xr1[r];
        }
        // next pair's z-store writes own slots only -> no barrier needed
    }
}

extern "C" void kernel_launch(void* const* d_in, const int* in_sizes, int n_in,
                              void* d_out, int out_size, void* d_ws, size_t ws_size,
                              hipStream_t stream)
{
    const float* x  = (const float*)d_in[0];
    const float* k  = (const float*)d_in[1];
    const float* D  = (const float*)d_in[2];
    float* out = (float*)d_out;

    dim3 grid(Hdim);          // one block per h
    dim3 block(NTHR);
    hipLaunchKernelGGL(fftconv_kernel, grid, block, 0, stream, x, k, D, out);
}